// Round 5
// baseline (269.591 us; speedup 1.0000x reference)
//
#include <hip/hip_runtime.h>
#include <hip/hip_bf16.h>

#define BB 8
#define QQ 64
#define SS 64
#define TT 64
#define HH 8
#define DH 64
#define NHID 512
#define STAT_K 8
#define TOKEN_K 16

typedef short bf16x8 __attribute__((ext_vector_type(8)));
typedef float f32x4 __attribute__((ext_vector_type(4)));

__device__ inline ushort f2bf_rne(float x) {
    union { float f; unsigned u; } v; v.f = x;
    unsigned r = v.u + 0x7fff + ((v.u >> 16) & 1);
    return (ushort)(r >> 16);
}
__device__ inline float bf2f(ushort h) {
    union { unsigned u; float f; } v; v.u = ((unsigned)h) << 16;
    return v.f;
}

// ---------------------------------------------------------------------------
// Transpose+split the six 512x512 weights into bf16 hi/lo planes:
// per z: hi[n][k] (262144 ush) then lo[n][k].
// ---------------------------------------------------------------------------
__global__ __launch_bounds__(256) void conv_w(
    const float* w0, const float* w1, const float* w2,
    const float* w3, const float* w4, const float* w5, ushort* wT)
{
    const int z = blockIdx.z;
    const float* srcs[6] = {w0, w1, w2, w3, w4, w5};
    const float* src = srcs[z];
    ushort* hi = wT + (size_t)z * 524288;
    ushort* lo = hi + 262144;
    __shared__ float t[32][33];
    const int c0 = blockIdx.x * 32, r0 = blockIdx.y * 32;
    const int tx = threadIdx.x & 31, ty = threadIdx.x >> 5;  // ty 0..7
    #pragma unroll
    for (int i = 0; i < 4; ++i)
        t[ty + 8 * i][tx] = src[(r0 + ty + 8 * i) * 512 + c0 + tx];
    __syncthreads();
    #pragma unroll
    for (int i = 0; i < 4; ++i) {
        float x = t[tx][ty + 8 * i];
        ushort h = f2bf_rne(x);
        int o = (c0 + ty + 8 * i) * 512 + r0 + tx;
        hi[o] = h;
        lo[o] = f2bf_rne(x - bf2f(h));
    }
}

// ---------------------------------------------------------------------------
// z-batched split-bf16 MFMA GEMM (fp32-equivalent): 512x512x512, fp32 A
// converted to hi/lo in the staging path (bit-identical to a separate split
// pass). Register-prefetch software pipeline (1 block/CU -> latency-bound).
// z=0: q @ Wq_stat -> q_stat ; z=1: sk @ Wk_stat -> k_stat ;
// z=2: q @ Wq_token -> q_tokf.
// ---------------------------------------------------------------------------
__global__ __launch_bounds__(256) void gemm_split3(
    const float* __restrict__ queries, const float* __restrict__ stat_keys,
    const ushort* __restrict__ wT,
    float* __restrict__ q_stat, float* __restrict__ k_stat,
    float* __restrict__ q_tokf)
{
    const int z = blockIdx.z;
    const float* Afp = (z == 1) ? stat_keys : queries;
    const ushort* Bh = wT + (size_t)z * 524288;
    const ushort* Bl = Bh + 262144;
    float* C = (z == 0) ? q_stat : (z == 1) ? k_stat : q_tokf;
    const int K = 512, N = 512;

    __shared__ ushort As[2][64][40];
    __shared__ ushort Bs[2][64][40];
    const int tid = threadIdx.x;
    const int row0 = blockIdx.y * 64, col0 = blockIdx.x * 64;
    const int wave = tid >> 6, lane = tid & 63;
    const int wm = wave & 1, wn = wave >> 1;
    const int m16 = lane & 15, quad = lane >> 4;
    const int srow = tid >> 2, schunk = tid & 3;

    const float*  aptr  = Afp + (size_t)(row0 + srow) * K + schunk * 8;
    const ushort* bptrh = Bh + (size_t)(col0 + srow) * K + schunk * 8;
    const ushort* bptrl = Bl + (size_t)(col0 + srow) * K + schunk * 8;

    // prefetch k0 = 0
    float4 ax0 = ((const float4*)aptr)[0];
    float4 ax1 = ((const float4*)aptr)[1];
    uint4  bvh = *(const uint4*)bptrh;
    uint4  bvl = *(const uint4*)bptrl;

    f32x4 acc[2][2];
    #pragma unroll
    for (int i = 0; i < 2; ++i)
        #pragma unroll
        for (int j = 0; j < 2; ++j)
            #pragma unroll
            for (int r = 0; r < 4; ++r) acc[i][j][r] = 0.f;

    for (int k0 = 0; k0 < K; k0 += 32) {
        ushort4 h0, h1, l0, l1;
        h0.x = f2bf_rne(ax0.x); l0.x = f2bf_rne(ax0.x - bf2f(h0.x));
        h0.y = f2bf_rne(ax0.y); l0.y = f2bf_rne(ax0.y - bf2f(h0.y));
        h0.z = f2bf_rne(ax0.z); l0.z = f2bf_rne(ax0.z - bf2f(h0.z));
        h0.w = f2bf_rne(ax0.w); l0.w = f2bf_rne(ax0.w - bf2f(h0.w));
        h1.x = f2bf_rne(ax1.x); l1.x = f2bf_rne(ax1.x - bf2f(h1.x));
        h1.y = f2bf_rne(ax1.y); l1.y = f2bf_rne(ax1.y - bf2f(h1.y));
        h1.z = f2bf_rne(ax1.z); l1.z = f2bf_rne(ax1.z - bf2f(h1.z));
        h1.w = f2bf_rne(ax1.w); l1.w = f2bf_rne(ax1.w - bf2f(h1.w));
        *(ushort4*)&As[0][srow][schunk * 8]     = h0;
        *(ushort4*)&As[0][srow][schunk * 8 + 4] = h1;
        *(ushort4*)&As[1][srow][schunk * 8]     = l0;
        *(ushort4*)&As[1][srow][schunk * 8 + 4] = l1;
        *(uint4*)&Bs[0][srow][schunk * 8] = bvh;
        *(uint4*)&Bs[1][srow][schunk * 8] = bvl;
        __syncthreads();

        if (k0 + 32 < K) {   // prefetch next K-step; overlaps MFMA phase
            ax0 = ((const float4*)(aptr + k0 + 32))[0];
            ax1 = ((const float4*)(aptr + k0 + 32))[1];
            bvh = *(const uint4*)(bptrh + k0 + 32);
            bvl = *(const uint4*)(bptrl + k0 + 32);
        }

        bf16x8 af[2], bf[2], afl[2], bfl[2];
        #pragma unroll
        for (int i = 0; i < 2; ++i) {
            af[i]  = *(const bf16x8*)&As[0][wm * 32 + i * 16 + m16][quad * 8];
            bf[i]  = *(const bf16x8*)&Bs[0][wn * 32 + i * 16 + m16][quad * 8];
            afl[i] = *(const bf16x8*)&As[1][wm * 32 + i * 16 + m16][quad * 8];
            bfl[i] = *(const bf16x8*)&Bs[1][wn * 32 + i * 16 + m16][quad * 8];
        }
        #pragma unroll
        for (int i = 0; i < 2; ++i)
            #pragma unroll
            for (int j = 0; j < 2; ++j) {
                acc[i][j] = __builtin_amdgcn_mfma_f32_16x16x32_bf16(af[i], bf[j], acc[i][j], 0, 0, 0);
                acc[i][j] = __builtin_amdgcn_mfma_f32_16x16x32_bf16(af[i], bfl[j], acc[i][j], 0, 0, 0);
                acc[i][j] = __builtin_amdgcn_mfma_f32_16x16x32_bf16(afl[i], bf[j], acc[i][j], 0, 0, 0);
            }
        __syncthreads();
    }

    #pragma unroll
    for (int i = 0; i < 2; ++i)
        #pragma unroll
        for (int j = 0; j < 2; ++j) {
            int r0 = row0 + wm * 32 + i * 16 + quad * 4;
            int c = col0 + wn * 32 + j * 16 + m16;
            #pragma unroll
            for (int reg = 0; reg < 4; ++reg)
                C[(size_t)(r0 + reg) * N + c] = acc[i][j][reg];
        }
}

// ---------------------------------------------------------------------------
// Final split GEMM: out = ctx(hi/lo) @ Wo(hi/lo), 512x512x512 -> fp32.
// Same register-prefetch pipeline.
// ---------------------------------------------------------------------------
__global__ __launch_bounds__(256) void gemm_out(
    const ushort* __restrict__ Ah, const ushort* __restrict__ Al,
    const ushort* __restrict__ Bh, const ushort* __restrict__ Bl,
    float* __restrict__ C)
{
    const int K = 512, N = 512;
    __shared__ ushort As[2][64][40];
    __shared__ ushort Bs[2][64][40];
    const int tid = threadIdx.x;
    const int row0 = blockIdx.y * 64, col0 = blockIdx.x * 64;
    const int wave = tid >> 6, lane = tid & 63;
    const int wm = wave & 1, wn = wave >> 1;
    const int m16 = lane & 15, quad = lane >> 4;
    const int srow = tid >> 2, schunk = tid & 3;

    const ushort* aptrh = Ah + (size_t)(row0 + srow) * K + schunk * 8;
    const ushort* aptrl = Al + (size_t)(row0 + srow) * K + schunk * 8;
    const ushort* bptrh = Bh + (size_t)(col0 + srow) * K + schunk * 8;
    const ushort* bptrl = Bl + (size_t)(col0 + srow) * K + schunk * 8;

    uint4 avh = *(const uint4*)aptrh;
    uint4 avl = *(const uint4*)aptrl;
    uint4 bvh = *(const uint4*)bptrh;
    uint4 bvl = *(const uint4*)bptrl;

    f32x4 acc[2][2];
    #pragma unroll
    for (int i = 0; i < 2; ++i)
        #pragma unroll
        for (int j = 0; j < 2; ++j)
            #pragma unroll
            for (int r = 0; r < 4; ++r) acc[i][j][r] = 0.f;

    for (int k0 = 0; k0 < K; k0 += 32) {
        *(uint4*)&As[0][srow][schunk * 8] = avh;
        *(uint4*)&As[1][srow][schunk * 8] = avl;
        *(uint4*)&Bs[0][srow][schunk * 8] = bvh;
        *(uint4*)&Bs[1][srow][schunk * 8] = bvl;
        __syncthreads();

        if (k0 + 32 < K) {
            avh = *(const uint4*)(aptrh + k0 + 32);
            avl = *(const uint4*)(aptrl + k0 + 32);
            bvh = *(const uint4*)(bptrh + k0 + 32);
            bvl = *(const uint4*)(bptrl + k0 + 32);
        }

        bf16x8 af[2], bf[2], afl[2], bfl[2];
        #pragma unroll
        for (int i = 0; i < 2; ++i) {
            af[i]  = *(const bf16x8*)&As[0][wm * 32 + i * 16 + m16][quad * 8];
            bf[i]  = *(const bf16x8*)&Bs[0][wn * 32 + i * 16 + m16][quad * 8];
            afl[i] = *(const bf16x8*)&As[1][wm * 32 + i * 16 + m16][quad * 8];
            bfl[i] = *(const bf16x8*)&Bs[1][wn * 32 + i * 16 + m16][quad * 8];
        }
        #pragma unroll
        for (int i = 0; i < 2; ++i)
            #pragma unroll
            for (int j = 0; j < 2; ++j) {
                acc[i][j] = __builtin_amdgcn_mfma_f32_16x16x32_bf16(af[i], bf[j], acc[i][j], 0, 0, 0);
                acc[i][j] = __builtin_amdgcn_mfma_f32_16x16x32_bf16(af[i], bfl[j], acc[i][j], 0, 0, 0);
                acc[i][j] = __builtin_amdgcn_mfma_f32_16x16x32_bf16(afl[i], bf[j], acc[i][j], 0, 0, 0);
            }
        __syncthreads();
    }

    #pragma unroll
    for (int i = 0; i < 2; ++i)
        #pragma unroll
        for (int j = 0; j < 2; ++j) {
            int r0 = row0 + wm * 32 + i * 16 + quad * 4;
            int c = col0 + wn * 32 + j * 16 + m16;
            #pragma unroll
            for (int reg = 0; reg < 4; ++reg)
                C[(size_t)(r0 + reg) * N + c] = acc[i][j][reg];
        }
}

// ---------------------------------------------------------------------------
// Token projections: 64x256 tile (4 waves in N), fused fp32->bf16 A staging,
// register-prefetch pipeline. A rows = last-16-token slices:
// GEMM row r -> global row (r>>4)*64 + 48 + (r&15).
// z=0: token_keys @ Wk_token -> k_tok ; z=1: values @ Wv -> v_proj.
// ---------------------------------------------------------------------------
__global__ __launch_bounds__(256) void gemm_tok(
    const float* __restrict__ token_keys, const float* __restrict__ values,
    const ushort* __restrict__ wkt_h, const ushort* __restrict__ wv_h,
    ushort* __restrict__ k_tok, ushort* __restrict__ v_proj)
{
    const int z = blockIdx.z;
    const float* A = z ? values : token_keys;
    const ushort* Bh = z ? wv_h : wkt_h;
    ushort* C = z ? v_proj : k_tok;
    const int K = 512, N = 512;

    __shared__ ushort As[64][40];
    __shared__ ushort Bs[256][40];
    const int tid = threadIdx.x;
    const int row0 = blockIdx.y * 64, col0 = blockIdx.x * 256;
    const int wave = tid >> 6, lane = tid & 63;
    const int m16 = lane & 15, quad = lane >> 4;
    const int srow = tid >> 2, schunk = tid & 3;

    const int r = row0 + srow;
    const float* aptr = A + (size_t)((r >> 4) * 64 + 48 + (r & 15)) * K + schunk * 8;

    float4 ax0 = ((const float4*)aptr)[0];
    float4 ax1 = ((const float4*)aptr)[1];
    uint4 bv[4];
    #pragma unroll
    for (int i = 0; i < 4; ++i) {
        int v = tid + i * 256;
        bv[i] = *(const uint4*)(Bh + (size_t)(col0 + (v >> 2)) * K + (v & 3) * 8);
    }

    f32x4 acc[4][4];
    #pragma unroll
    for (int i = 0; i < 4; ++i)
        #pragma unroll
        for (int j = 0; j < 4; ++j)
            #pragma unroll
            for (int rr = 0; rr < 4; ++rr) acc[i][j][rr] = 0.f;

    for (int k0 = 0; k0 < K; k0 += 32) {
        ushort4 h0, h1;
        h0.x = f2bf_rne(ax0.x); h0.y = f2bf_rne(ax0.y);
        h0.z = f2bf_rne(ax0.z); h0.w = f2bf_rne(ax0.w);
        h1.x = f2bf_rne(ax1.x); h1.y = f2bf_rne(ax1.y);
        h1.z = f2bf_rne(ax1.z); h1.w = f2bf_rne(ax1.w);
        *(ushort4*)&As[srow][schunk * 8]     = h0;
        *(ushort4*)&As[srow][schunk * 8 + 4] = h1;
        #pragma unroll
        for (int i = 0; i < 4; ++i) {
            int v = tid + i * 256;
            *(uint4*)&Bs[v >> 2][(v & 3) * 8] = bv[i];
        }
        __syncthreads();

        if (k0 + 32 < K) {
            ax0 = ((const float4*)(aptr + k0 + 32))[0];
            ax1 = ((const float4*)(aptr + k0 + 32))[1];
            #pragma unroll
            for (int i = 0; i < 4; ++i) {
                int v = tid + i * 256;
                bv[i] = *(const uint4*)(Bh + (size_t)(col0 + (v >> 2)) * K + (v & 3) * 8 + k0 + 32);
            }
        }

        bf16x8 af[4], bf[4];
        #pragma unroll
        for (int i = 0; i < 4; ++i) {
            af[i] = *(const bf16x8*)&As[i * 16 + m16][quad * 8];
            bf[i] = *(const bf16x8*)&Bs[wave * 64 + i * 16 + m16][quad * 8];
        }
        #pragma unroll
        for (int i = 0; i < 4; ++i)
            #pragma unroll
            for (int j = 0; j < 4; ++j)
                acc[i][j] = __builtin_amdgcn_mfma_f32_16x16x32_bf16(af[i], bf[j], acc[i][j], 0, 0, 0);
        __syncthreads();
    }

    #pragma unroll
    for (int i = 0; i < 4; ++i)
        #pragma unroll
        for (int j = 0; j < 4; ++j) {
            int r0 = row0 + i * 16 + quad * 4;
            int c = col0 + wave * 64 + j * 16 + m16;
            #pragma unroll
            for (int reg = 0; reg < 4; ++reg)
                C[(size_t)(r0 + reg) * N + c] = f2bf_rne(acc[i][j][reg]);
        }
}

// ---------------------------------------------------------------------------
// FUSED: stat scores + valid-len mask + top-8 + softmax, then token
// attention over the selected segments. One wave per (b,h,q). Top-8 results
// live in wave-uniform registers (no global round-trip). Writes ctx hi/lo.
// ---------------------------------------------------------------------------
__global__ __launch_bounds__(64) void attend_fused(
    const float* __restrict__ q_stat, const float* __restrict__ k_stat,
    const float* __restrict__ q_tok, const ushort* __restrict__ k_tok,
    const ushort* __restrict__ v_proj, const int* __restrict__ valid_lens,
    ushort* __restrict__ ctx_hi, ushort* __restrict__ ctx_lo)
{
    const int bid = blockIdx.x;           // b*512 + h*64 + q
    const int b = bid >> 9, h = (bid >> 6) & 7, q = bid & 63;
    const int lane = threadIdx.x;

    __shared__ float sq[64];
    __shared__ float ssc[16];

    // ---- stat scores: lane = segment s ----
    sq[lane] = q_stat[(b * QQ + q) * NHID + h * DH + lane];
    __syncthreads();
    {
        const float4* kr = (const float4*)(k_stat + (b * SS + lane) * NHID + h * DH);
        const float4* sq4 = (const float4*)sq;
        float sc = 0.f;
        #pragma unroll
        for (int i = 0; i < 16; ++i) {
            float4 a = sq4[i], kk = kr[i];
            sc += a.x * kk.x + a.y * kk.y + a.z * kk.z + a.w * kk.w;
        }
        sc *= 0.125f;
        if (lane >= valid_lens[b]) sc = -1e6f;

        // ---- top-8 (tie-break: smaller index, matches lax.top_k) ----
        float my = sc;
        float mv[STAT_K]; int mi[STAT_K];
        #pragma unroll
        for (int j = 0; j < STAT_K; ++j) {
            float v = my; int idx = lane;
            #pragma unroll
            for (int off = 32; off > 0; off >>= 1) {
                float ov = __shfl_down(v, off);
                int   oi = __shfl_down(idx, off);
                if (ov > v || (ov == v && oi < idx)) { v = ov; idx = oi; }
            }
            v = __shfl(v, 0); idx = __shfl(idx, 0);
            mv[j] = v; mi[j] = idx;
            if (lane == idx) my = -3e38f;
        }
        float m0 = mv[0], den = 0.f, w[STAT_K];
        #pragma unroll
        for (int j = 0; j < STAT_K; ++j) { w[j] = __expf(mv[j] - m0); den += w[j]; }
        float inv = 1.f / den;

        // ---- token path: reload sq with q_tok ----
        __syncthreads();
        sq[lane] = q_tok[(size_t)(b * QQ + q) * NHID + h * DH + lane];
        __syncthreads();

        const int t = lane >> 2, part = lane & 3;   // 16 tokens x 4 lanes
        float acc = 0.f;

        #pragma unroll
        for (int j = 0; j < STAT_K; ++j) {
            const int s = mi[j];
            const float wseg = w[j] * inv;
            const size_t rowbase = (size_t)((b * SS + s) * TOKEN_K);

            const uint4* k4 = (const uint4*)(k_tok + (rowbase + t) * NHID + h * DH + part * 16);
            uint4 ka = k4[0], kb = k4[1];
            const float* qb = &sq[part * 16];
            float p = 0.f;
            p += qb[0]  * bf2f((ushort)(ka.x & 0xffff)) + qb[1]  * bf2f((ushort)(ka.x >> 16));
            p += qb[2]  * bf2f((ushort)(ka.y & 0xffff)) + qb[3]  * bf2f((ushort)(ka.y >> 16));
            p += qb[4]  * bf2f((ushort)(ka.z & 0xffff)) + qb[5]  * bf2f((ushort)(ka.z >> 16));
            p += qb[6]  * bf2f((ushort)(ka.w & 0xffff)) + qb[7]  * bf2f((ushort)(ka.w >> 16));
            p += qb[8]  * bf2f((ushort)(kb.x & 0xffff)) + qb[9]  * bf2f((ushort)(kb.x >> 16));
            p += qb[10] * bf2f((ushort)(kb.y & 0xffff)) + qb[11] * bf2f((ushort)(kb.y >> 16));
            p += qb[12] * bf2f((ushort)(kb.z & 0xffff)) + qb[13] * bf2f((ushort)(kb.z >> 16));
            p += qb[14] * bf2f((ushort)(kb.w & 0xffff)) + qb[15] * bf2f((ushort)(kb.w >> 16));
            p += __shfl_xor(p, 1);
            p += __shfl_xor(p, 2);
            if (part == 0) ssc[t] = p * 0.125f;
            __syncthreads();

            float m = ssc[0];
            #pragma unroll
            for (int tt = 1; tt < TOKEN_K; ++tt) m = fmaxf(m, ssc[tt]);
            float dent = 0.f, wv[TOKEN_K];
            #pragma unroll
            for (int tt = 0; tt < TOKEN_K; ++tt) { wv[tt] = __expf(ssc[tt] - m); dent += wv[tt]; }

            const ushort* vrow = v_proj + rowbase * NHID + h * DH + lane;
            float loc = 0.f;
            #pragma unroll
            for (int tt = 0; tt < TOKEN_K; ++tt) loc += wv[tt] * bf2f(vrow[tt * NHID]);
            acc += (wseg / dent) * loc;
            __syncthreads();
        }

        const size_t o = (size_t)(b * QQ + q) * NHID + h * DH + lane;
        ushort hh = f2bf_rne(acc);
        ctx_hi[o] = hh;
        ctx_lo[o] = f2bf_rne(acc - bf2f(hh));
    }
}

extern "C" void kernel_launch(void* const* d_in, const int* in_sizes, int n_in,
                              void* d_out, int out_size, void* d_ws, size_t ws_size,
                              hipStream_t stream) {
    const float* queries    = (const float*)d_in[0];
    const float* stat_keys  = (const float*)d_in[1];
    const float* token_keys = (const float*)d_in[2];
    const float* values     = (const float*)d_in[3];
    const int*   valid_lens = (const int*)d_in[4];
    const float* Wq_stat    = (const float*)d_in[5];
    const float* Wq_token   = (const float*)d_in[6];
    const float* Wk_stat    = (const float*)d_in[7];
    const float* Wk_token   = (const float*)d_in[8];
    const float* Wv         = (const float*)d_in[9];
    const float* Wo         = (const float*)d_in[10];

    char* w = (char*)d_ws;
    ushort* wT      = (ushort*)(w + 0);            // 6 x (hi+lo) x 262144 ush = 6 MB
    float*  q_stat  = (float*)(w + 6291456);       // 1 MB
    float*  k_stat  = (float*)(w + 7340032);       // 1 MB
    float*  q_tokf  = (float*)(w + 8388608);       // 1 MB
    ushort* k_tok   = (ushort*)(w + 9437184);      // bf16 [8192,512] = 8 MB
    ushort* v_projp = (ushort*)(w + 17825792);     // bf16 [8192,512] = 8 MB
    ushort* ctx_hi  = (ushort*)(w + 26214400);     // 512 KB
    ushort* ctx_lo  = ctx_hi + 262144;             // 512 KB

    // weight order in wT: 0=Wq_stat 1=Wk_stat 2=Wq_token 3=Wk_token 4=Wv 5=Wo
    ushort* wkt_h = wT + 3 * 524288;
    ushort* wv_h  = wT + 4 * 524288;
    ushort* wo_h  = wT + 5 * 524288, *wo_l = wo_h + 262144;

    // 1. weight transpose+split (bf16 hi/lo planes)
    conv_w<<<dim3(16, 16, 6), 256, 0, stream>>>(
        Wq_stat, Wk_stat, Wq_token, Wk_token, Wv, Wo, wT);

    // 2. three split-precision projections (A converted inline from fp32)
    gemm_split3<<<dim3(8, 8, 3), 256, 0, stream>>>(
        queries, stat_keys, wT, q_stat, k_stat, q_tokf);

    // 3. token-path projections (64x256 tiles, pipelined)
    gemm_tok<<<dim3(2, 128, 2), 256, 0, stream>>>(
        token_keys, values, wkt_h, wv_h, k_tok, v_projp);

    // 4. fused stat top-8 + token attention -> ctx (hi/lo planes)
    attend_fused<<<4096, 64, 0, stream>>>(
        q_stat, k_stat, q_tokf, k_tok, v_projp, valid_lens, ctx_hi, ctx_lo);

    // 5. output projection
    gemm_out<<<dim3(8, 8), 256, 0, stream>>>(
        ctx_hi, ctx_lo, wo_h, wo_l, (float*)d_out);
}

// Round 6
// 251.947 us; speedup vs baseline: 1.0700x; 1.0700x over previous
//
#include <hip/hip_runtime.h>
#include <hip/hip_bf16.h>

#define BB 8
#define QQ 64
#define SS 64
#define TT 64
#define HH 8
#define DH 64
#define NHID 512
#define STAT_K 8
#define TOKEN_K 16

typedef short bf16x8 __attribute__((ext_vector_type(8)));
typedef float f32x4 __attribute__((ext_vector_type(4)));

__device__ inline ushort f2bf_rne(float x) {
    union { float f; unsigned u; } v; v.f = x;
    unsigned r = v.u + 0x7fff + ((v.u >> 16) & 1);
    return (ushort)(r >> 16);
}
__device__ inline float bf2f(ushort h) {
    union { unsigned u; float f; } v; v.u = ((unsigned)h) << 16;
    return v.f;
}

// ---------------------------------------------------------------------------
// Transpose+split the six 512x512 weights into bf16 hi/lo planes:
// per z: hi[n][k] (262144 ush) then lo[n][k].
// ---------------------------------------------------------------------------
__global__ __launch_bounds__(256) void conv_w(
    const float* w0, const float* w1, const float* w2,
    const float* w3, const float* w4, const float* w5, ushort* wT)
{
    const int z = blockIdx.z;
    const float* srcs[6] = {w0, w1, w2, w3, w4, w5};
    const float* src = srcs[z];
    ushort* hi = wT + (size_t)z * 524288;
    ushort* lo = hi + 262144;
    __shared__ float t[32][33];
    const int c0 = blockIdx.x * 32, r0 = blockIdx.y * 32;
    const int tx = threadIdx.x & 31, ty = threadIdx.x >> 5;  // ty 0..7
    #pragma unroll
    for (int i = 0; i < 4; ++i)
        t[ty + 8 * i][tx] = src[(r0 + ty + 8 * i) * 512 + c0 + tx];
    __syncthreads();
    #pragma unroll
    for (int i = 0; i < 4; ++i) {
        float x = t[tx][ty + 8 * i];
        ushort h = f2bf_rne(x);
        int o = (c0 + ty + 8 * i) * 512 + r0 + tx;
        hi[o] = h;
        lo[o] = f2bf_rne(x - bf2f(h));
    }
}

// ---------------------------------------------------------------------------
// z-batched split-bf16 MFMA GEMM (fp32-equivalent): 512x512x512. fp32 A is
// converted to hi/lo inline in the staging path (bit-identical to a separate
// split pass). NO register prefetch — R5 showed hand-pipelining regresses
// 2x on this structure; compiler schedules loads-after-barrier better.
// z=0: q @ Wq_stat ; z=1: sk @ Wk_stat ; z=2: q @ Wq_token.
// ---------------------------------------------------------------------------
__global__ __launch_bounds__(256) void gemm_split3(
    const float* __restrict__ queries, const float* __restrict__ stat_keys,
    const ushort* __restrict__ wT,
    float* __restrict__ q_stat, float* __restrict__ k_stat,
    float* __restrict__ q_tokf)
{
    const int z = blockIdx.z;
    const float* Afp = (z == 1) ? stat_keys : queries;
    const ushort* Bh = wT + (size_t)z * 524288;
    const ushort* Bl = Bh + 262144;
    float* C = (z == 0) ? q_stat : (z == 1) ? k_stat : q_tokf;
    const int K = 512, N = 512;

    __shared__ ushort As[2][64][40];
    __shared__ ushort Bs[2][64][40];
    const int tid = threadIdx.x;
    const int row0 = blockIdx.y * 64, col0 = blockIdx.x * 64;
    const int wave = tid >> 6, lane = tid & 63;
    const int wm = wave & 1, wn = wave >> 1;
    const int m16 = lane & 15, quad = lane >> 4;
    const int srow = tid >> 2, schunk = tid & 3;

    const float*  aptr  = Afp + (size_t)(row0 + srow) * K + schunk * 8;
    const ushort* bptrh = Bh + (size_t)(col0 + srow) * K + schunk * 8;
    const ushort* bptrl = Bl + (size_t)(col0 + srow) * K + schunk * 8;

    f32x4 acc[2][2];
    #pragma unroll
    for (int i = 0; i < 2; ++i)
        #pragma unroll
        for (int j = 0; j < 2; ++j)
            #pragma unroll
            for (int r = 0; r < 4; ++r) acc[i][j][r] = 0.f;

    for (int k0 = 0; k0 < K; k0 += 32) {
        float4 ax0 = ((const float4*)(aptr + k0))[0];
        float4 ax1 = ((const float4*)(aptr + k0))[1];
        uint4  bvh = *(const uint4*)(bptrh + k0);
        uint4  bvl = *(const uint4*)(bptrl + k0);
        ushort4 h0, h1, l0, l1;
        h0.x = f2bf_rne(ax0.x); l0.x = f2bf_rne(ax0.x - bf2f(h0.x));
        h0.y = f2bf_rne(ax0.y); l0.y = f2bf_rne(ax0.y - bf2f(h0.y));
        h0.z = f2bf_rne(ax0.z); l0.z = f2bf_rne(ax0.z - bf2f(h0.z));
        h0.w = f2bf_rne(ax0.w); l0.w = f2bf_rne(ax0.w - bf2f(h0.w));
        h1.x = f2bf_rne(ax1.x); l1.x = f2bf_rne(ax1.x - bf2f(h1.x));
        h1.y = f2bf_rne(ax1.y); l1.y = f2bf_rne(ax1.y - bf2f(h1.y));
        h1.z = f2bf_rne(ax1.z); l1.z = f2bf_rne(ax1.z - bf2f(h1.z));
        h1.w = f2bf_rne(ax1.w); l1.w = f2bf_rne(ax1.w - bf2f(h1.w));
        *(ushort4*)&As[0][srow][schunk * 8]     = h0;
        *(ushort4*)&As[0][srow][schunk * 8 + 4] = h1;
        *(ushort4*)&As[1][srow][schunk * 8]     = l0;
        *(ushort4*)&As[1][srow][schunk * 8 + 4] = l1;
        *(uint4*)&Bs[0][srow][schunk * 8] = bvh;
        *(uint4*)&Bs[1][srow][schunk * 8] = bvl;
        __syncthreads();

        bf16x8 af[2], bf[2], afl[2], bfl[2];
        #pragma unroll
        for (int i = 0; i < 2; ++i) {
            af[i]  = *(const bf16x8*)&As[0][wm * 32 + i * 16 + m16][quad * 8];
            bf[i]  = *(const bf16x8*)&Bs[0][wn * 32 + i * 16 + m16][quad * 8];
            afl[i] = *(const bf16x8*)&As[1][wm * 32 + i * 16 + m16][quad * 8];
            bfl[i] = *(const bf16x8*)&Bs[1][wn * 32 + i * 16 + m16][quad * 8];
        }
        #pragma unroll
        for (int i = 0; i < 2; ++i)
            #pragma unroll
            for (int j = 0; j < 2; ++j) {
                acc[i][j] = __builtin_amdgcn_mfma_f32_16x16x32_bf16(af[i], bf[j], acc[i][j], 0, 0, 0);
                acc[i][j] = __builtin_amdgcn_mfma_f32_16x16x32_bf16(af[i], bfl[j], acc[i][j], 0, 0, 0);
                acc[i][j] = __builtin_amdgcn_mfma_f32_16x16x32_bf16(afl[i], bf[j], acc[i][j], 0, 0, 0);
            }
        __syncthreads();
    }

    #pragma unroll
    for (int i = 0; i < 2; ++i)
        #pragma unroll
        for (int j = 0; j < 2; ++j) {
            int r0 = row0 + wm * 32 + i * 16 + quad * 4;
            int c = col0 + wn * 32 + j * 16 + m16;
            #pragma unroll
            for (int reg = 0; reg < 4; ++reg)
                C[(size_t)(r0 + reg) * N + c] = acc[i][j][reg];
        }
}

// ---------------------------------------------------------------------------
// Final split GEMM: out = ctx(hi/lo) @ Wo(hi/lo), 512x512x512 -> fp32.
// Load-after-barrier (no prefetch).
// ---------------------------------------------------------------------------
__global__ __launch_bounds__(256) void gemm_out(
    const ushort* __restrict__ Ah, const ushort* __restrict__ Al,
    const ushort* __restrict__ Bh, const ushort* __restrict__ Bl,
    float* __restrict__ C)
{
    const int K = 512, N = 512;
    __shared__ ushort As[2][64][40];
    __shared__ ushort Bs[2][64][40];
    const int tid = threadIdx.x;
    const int row0 = blockIdx.y * 64, col0 = blockIdx.x * 64;
    const int wave = tid >> 6, lane = tid & 63;
    const int wm = wave & 1, wn = wave >> 1;
    const int m16 = lane & 15, quad = lane >> 4;
    const int srow = tid >> 2, schunk = tid & 3;

    f32x4 acc[2][2];
    #pragma unroll
    for (int i = 0; i < 2; ++i)
        #pragma unroll
        for (int j = 0; j < 2; ++j)
            #pragma unroll
            for (int r = 0; r < 4; ++r) acc[i][j][r] = 0.f;

    for (int k0 = 0; k0 < K; k0 += 32) {
        const size_t aoff = (size_t)(row0 + srow) * K + k0 + schunk * 8;
        const size_t boff = (size_t)(col0 + srow) * K + k0 + schunk * 8;
        *(uint4*)&As[0][srow][schunk * 8] = *(const uint4*)(Ah + aoff);
        *(uint4*)&Bs[0][srow][schunk * 8] = *(const uint4*)(Bh + boff);
        *(uint4*)&As[1][srow][schunk * 8] = *(const uint4*)(Al + aoff);
        *(uint4*)&Bs[1][srow][schunk * 8] = *(const uint4*)(Bl + boff);
        __syncthreads();

        bf16x8 af[2], bf[2], afl[2], bfl[2];
        #pragma unroll
        for (int i = 0; i < 2; ++i) {
            af[i]  = *(const bf16x8*)&As[0][wm * 32 + i * 16 + m16][quad * 8];
            bf[i]  = *(const bf16x8*)&Bs[0][wn * 32 + i * 16 + m16][quad * 8];
            afl[i] = *(const bf16x8*)&As[1][wm * 32 + i * 16 + m16][quad * 8];
            bfl[i] = *(const bf16x8*)&Bs[1][wn * 32 + i * 16 + m16][quad * 8];
        }
        #pragma unroll
        for (int i = 0; i < 2; ++i)
            #pragma unroll
            for (int j = 0; j < 2; ++j) {
                acc[i][j] = __builtin_amdgcn_mfma_f32_16x16x32_bf16(af[i], bf[j], acc[i][j], 0, 0, 0);
                acc[i][j] = __builtin_amdgcn_mfma_f32_16x16x32_bf16(af[i], bfl[j], acc[i][j], 0, 0, 0);
                acc[i][j] = __builtin_amdgcn_mfma_f32_16x16x32_bf16(afl[i], bf[j], acc[i][j], 0, 0, 0);
            }
        __syncthreads();
    }

    #pragma unroll
    for (int i = 0; i < 2; ++i)
        #pragma unroll
        for (int j = 0; j < 2; ++j) {
            int r0 = row0 + wm * 32 + i * 16 + quad * 4;
            int c = col0 + wn * 32 + j * 16 + m16;
            #pragma unroll
            for (int reg = 0; reg < 4; ++reg)
                C[(size_t)(r0 + reg) * N + c] = acc[i][j][reg];
        }
}

// ---------------------------------------------------------------------------
// Token projections (R4 structure — the fast one): 64x256 block tile
// (4 waves side-by-side in N, each wave 64x64 = 4x4 frags), fused fp32->bf16
// in A staging, loads issued at loop top (compiler-scheduled). A rows map to
// last-16-token slices: GEMM row r -> global row (r>>4)*64 + 48 + (r&15).
// z=0: token_keys @ Wk_token -> k_tok ; z=1: values @ Wv -> v_proj.
// ---------------------------------------------------------------------------
__global__ __launch_bounds__(256) void gemm_tok(
    const float* __restrict__ token_keys, const float* __restrict__ values,
    const ushort* __restrict__ wkt_h, const ushort* __restrict__ wv_h,
    ushort* __restrict__ k_tok, ushort* __restrict__ v_proj)
{
    const int z = blockIdx.z;
    const float* A = z ? values : token_keys;
    const ushort* Bh = z ? wv_h : wkt_h;
    ushort* C = z ? v_proj : k_tok;
    const int K = 512, N = 512;

    __shared__ ushort As[64][40];
    __shared__ ushort Bs[256][40];
    const int tid = threadIdx.x;
    const int row0 = blockIdx.y * 64, col0 = blockIdx.x * 256;
    const int wave = tid >> 6, lane = tid & 63;
    const int m16 = lane & 15, quad = lane >> 4;
    const int srow = tid >> 2, schunk = tid & 3;

    const int r = row0 + srow;
    const size_t arow = (size_t)((r >> 4) * 64 + 48 + (r & 15)) * K;

    f32x4 acc[4][4];
    #pragma unroll
    for (int i = 0; i < 4; ++i)
        #pragma unroll
        for (int j = 0; j < 4; ++j)
            #pragma unroll
            for (int rr = 0; rr < 4; ++rr) acc[i][j][rr] = 0.f;

    for (int k0 = 0; k0 < K; k0 += 32) {
        const float* ap = A + arow + k0 + schunk * 8;
        float4 x0 = ((const float4*)ap)[0];
        float4 x1 = ((const float4*)ap)[1];
        ushort4 h0, h1;
        h0.x = f2bf_rne(x0.x); h0.y = f2bf_rne(x0.y);
        h0.z = f2bf_rne(x0.z); h0.w = f2bf_rne(x0.w);
        h1.x = f2bf_rne(x1.x); h1.y = f2bf_rne(x1.y);
        h1.z = f2bf_rne(x1.z); h1.w = f2bf_rne(x1.w);
        *(ushort4*)&As[srow][schunk * 8] = h0;
        *(ushort4*)&As[srow][schunk * 8 + 4] = h1;
        #pragma unroll
        for (int i = 0; i < 4; ++i) {
            int v = tid + i * 256;
            int brow = v >> 2, bchunk = v & 3;
            *(uint4*)&Bs[brow][bchunk * 8] =
                *(const uint4*)(Bh + (size_t)(col0 + brow) * K + k0 + bchunk * 8);
        }
        __syncthreads();

        bf16x8 af[4], bf[4];
        #pragma unroll
        for (int i = 0; i < 4; ++i) {
            af[i] = *(const bf16x8*)&As[i * 16 + m16][quad * 8];
            bf[i] = *(const bf16x8*)&Bs[wave * 64 + i * 16 + m16][quad * 8];
        }
        #pragma unroll
        for (int i = 0; i < 4; ++i)
            #pragma unroll
            for (int j = 0; j < 4; ++j)
                acc[i][j] = __builtin_amdgcn_mfma_f32_16x16x32_bf16(af[i], bf[j], acc[i][j], 0, 0, 0);
        __syncthreads();
    }

    #pragma unroll
    for (int i = 0; i < 4; ++i)
        #pragma unroll
        for (int j = 0; j < 4; ++j) {
            int r0 = row0 + i * 16 + quad * 4;
            int c = col0 + wave * 64 + j * 16 + m16;
            #pragma unroll
            for (int reg = 0; reg < 4; ++reg)
                C[(size_t)(r0 + reg) * N + c] = f2bf_rne(acc[i][j][reg]);
        }
}

// ---------------------------------------------------------------------------
// FUSED: stat scores + valid-len mask + top-8 + softmax, then token
// attention over the selected segments. One wave per (b,h,q). Writes ctx
// hi/lo planes directly.
// ---------------------------------------------------------------------------
__global__ __launch_bounds__(64) void attend_fused(
    const float* __restrict__ q_stat, const float* __restrict__ k_stat,
    const float* __restrict__ q_tok, const ushort* __restrict__ k_tok,
    const ushort* __restrict__ v_proj, const int* __restrict__ valid_lens,
    ushort* __restrict__ ctx_hi, ushort* __restrict__ ctx_lo)
{
    const int bid = blockIdx.x;           // b*512 + h*64 + q
    const int b = bid >> 9, h = (bid >> 6) & 7, q = bid & 63;
    const int lane = threadIdx.x;

    __shared__ float sq[64];
    __shared__ float ssc[16];

    // ---- stat scores: lane = segment s ----
    sq[lane] = q_stat[(b * QQ + q) * NHID + h * DH + lane];
    __syncthreads();

    const float4* kr = (const float4*)(k_stat + (b * SS + lane) * NHID + h * DH);
    const float4* sq4 = (const float4*)sq;
    float sc = 0.f;
    #pragma unroll
    for (int i = 0; i < 16; ++i) {
        float4 a = sq4[i], kk = kr[i];
        sc += a.x * kk.x + a.y * kk.y + a.z * kk.z + a.w * kk.w;
    }
    sc *= 0.125f;
    if (lane >= valid_lens[b]) sc = -1e6f;

    // ---- top-8 (tie-break: smaller index, matches lax.top_k) ----
    float my = sc;
    float mv[STAT_K]; int mi[STAT_K];
    #pragma unroll
    for (int j = 0; j < STAT_K; ++j) {
        float v = my; int idx = lane;
        #pragma unroll
        for (int off = 32; off > 0; off >>= 1) {
            float ov = __shfl_down(v, off);
            int   oi = __shfl_down(idx, off);
            if (ov > v || (ov == v && oi < idx)) { v = ov; idx = oi; }
        }
        v = __shfl(v, 0); idx = __shfl(idx, 0);
        mv[j] = v; mi[j] = idx;
        if (lane == idx) my = -3e38f;
    }
    float m0 = mv[0], den = 0.f, w[STAT_K];
    #pragma unroll
    for (int j = 0; j < STAT_K; ++j) { w[j] = __expf(mv[j] - m0); den += w[j]; }
    float inv = 1.f / den;

    // ---- token path: reload sq with q_tok ----
    __syncthreads();
    sq[lane] = q_tok[(size_t)(b * QQ + q) * NHID + h * DH + lane];
    __syncthreads();

    const int t = lane >> 2, part = lane & 3;   // 16 tokens x 4 lanes
    float acc = 0.f;

    #pragma unroll
    for (int j = 0; j < STAT_K; ++j) {
        const int s = mi[j];
        const float wseg = w[j] * inv;
        const size_t rowbase = (size_t)((b * SS + s) * TOKEN_K);

        const uint4* k4 = (const uint4*)(k_tok + (rowbase + t) * NHID + h * DH + part * 16);
        uint4 ka = k4[0], kb = k4[1];
        const float* qb = &sq[part * 16];
        float p = 0.f;
        p += qb[0]  * bf2f((ushort)(ka.x & 0xffff)) + qb[1]  * bf2f((ushort)(ka.x >> 16));
        p += qb[2]  * bf2f((ushort)(ka.y & 0xffff)) + qb[3]  * bf2f((ushort)(ka.y >> 16));
        p += qb[4]  * bf2f((ushort)(ka.z & 0xffff)) + qb[5]  * bf2f((ushort)(ka.z >> 16));
        p += qb[6]  * bf2f((ushort)(ka.w & 0xffff)) + qb[7]  * bf2f((ushort)(ka.w >> 16));
        p += qb[8]  * bf2f((ushort)(kb.x & 0xffff)) + qb[9]  * bf2f((ushort)(kb.x >> 16));
        p += qb[10] * bf2f((ushort)(kb.y & 0xffff)) + qb[11] * bf2f((ushort)(kb.y >> 16));
        p += qb[12] * bf2f((ushort)(kb.z & 0xffff)) + qb[13] * bf2f((ushort)(kb.z >> 16));
        p += qb[14] * bf2f((ushort)(kb.w & 0xffff)) + qb[15] * bf2f((ushort)(kb.w >> 16));
        p += __shfl_xor(p, 1);
        p += __shfl_xor(p, 2);
        if (part == 0) ssc[t] = p * 0.125f;
        __syncthreads();

        float m = ssc[0];
        #pragma unroll
        for (int tt = 1; tt < TOKEN_K; ++tt) m = fmaxf(m, ssc[tt]);
        float dent = 0.f, wv[TOKEN_K];
        #pragma unroll
        for (int tt = 0; tt < TOKEN_K; ++tt) { wv[tt] = __expf(ssc[tt] - m); dent += wv[tt]; }

        const ushort* vrow = v_proj + rowbase * NHID + h * DH + lane;
        float loc = 0.f;
        #pragma unroll
        for (int tt = 0; tt < TOKEN_K; ++tt) loc += wv[tt] * bf2f(vrow[tt * NHID]);
        acc += (wseg / dent) * loc;
        __syncthreads();
    }

    const size_t o = (size_t)(b * QQ + q) * NHID + h * DH + lane;
    ushort hh = f2bf_rne(acc);
    ctx_hi[o] = hh;
    ctx_lo[o] = f2bf_rne(acc - bf2f(hh));
}

extern "C" void kernel_launch(void* const* d_in, const int* in_sizes, int n_in,
                              void* d_out, int out_size, void* d_ws, size_t ws_size,
                              hipStream_t stream) {
    const float* queries    = (const float*)d_in[0];
    const float* stat_keys  = (const float*)d_in[1];
    const float* token_keys = (const float*)d_in[2];
    const float* values     = (const float*)d_in[3];
    const int*   valid_lens = (const int*)d_in[4];
    const float* Wq_stat    = (const float*)d_in[5];
    const float* Wq_token   = (const float*)d_in[6];
    const float* Wk_stat    = (const float*)d_in[7];
    const float* Wk_token   = (const float*)d_in[8];
    const float* Wv         = (const float*)d_in[9];
    const float* Wo         = (const float*)d_in[10];

    char* w = (char*)d_ws;
    ushort* wT      = (ushort*)(w + 0);            // 6 x (hi+lo) x 262144 ush = 6 MB
    float*  q_stat  = (float*)(w + 6291456);       // 1 MB
    float*  k_stat  = (float*)(w + 7340032);       // 1 MB
    float*  q_tokf  = (float*)(w + 8388608);       // 1 MB
    ushort* k_tok   = (ushort*)(w + 9437184);      // bf16 [8192,512] = 8 MB
    ushort* v_projp = (ushort*)(w + 17825792);     // bf16 [8192,512] = 8 MB
    ushort* ctx_hi  = (ushort*)(w + 26214400);     // 512 KB
    ushort* ctx_lo  = ctx_hi + 262144;             // 512 KB

    // weight order in wT: 0=Wq_stat 1=Wk_stat 2=Wq_token 3=Wk_token 4=Wv 5=Wo
    ushort* wkt_h = wT + 3 * 524288;
    ushort* wv_h  = wT + 4 * 524288;
    ushort* wo_h  = wT + 5 * 524288, *wo_l = wo_h + 262144;

    // 1. weight transpose+split (bf16 hi/lo planes)
    conv_w<<<dim3(16, 16, 6), 256, 0, stream>>>(
        Wq_stat, Wk_stat, Wq_token, Wk_token, Wv, Wo, wT);

    // 2. three split-precision projections (A converted inline from fp32)
    gemm_split3<<<dim3(8, 8, 3), 256, 0, stream>>>(
        queries, stat_keys, wT, q_stat, k_stat, q_tokf);

    // 3. token-path projections (64x256 tiles, R4 structure)
    gemm_tok<<<dim3(2, 128, 2), 256, 0, stream>>>(
        token_keys, values, wkt_h, wv_h, k_tok, v_projp);

    // 4. fused stat top-8 + token attention -> ctx (hi/lo planes)
    attend_fused<<<4096, 64, 0, stream>>>(
        q_stat, k_stat, q_tokf, k_tok, v_projp, valid_lens, ctx_hi, ctx_lo);

    // 5. output projection
    gemm_out<<<dim3(8, 8), 256, 0, stream>>>(
        ctx_hi, ctx_lo, wo_h, wo_l, (float*)d_out);
}